// Round 1
// baseline (1323.063 us; speedup 1.0000x reference)
//
#include <hip/hip_runtime.h>

typedef unsigned short u16;
typedef _Float16 f16;
typedef __attribute__((ext_vector_type(2))) _Float16 f16x2;
typedef __attribute__((ext_vector_type(8))) _Float16 f16x8;
typedef __attribute__((ext_vector_type(4))) float f32x4;

#define D 128

// ---------------- fp32 -> fp16 convert (8 elems/thread) ----------------
__global__ __launch_bounds__(256) void k_convert(const float* __restrict__ in,
                                                 u16* __restrict__ out, int n8) {
  int i = blockIdx.x * 256 + threadIdx.x;
  if (i >= n8) return;
  const float4* ip = (const float4*)in;
  float4 a = ip[i * 2], b = ip[i * 2 + 1];
  f16x8 v = {(f16)a.x, (f16)a.y, (f16)a.z, (f16)a.w,
             (f16)b.x, (f16)b.y, (f16)b.z, (f16)b.w};
  *(f16x8*)(out + (size_t)i * 8) = v;
}

// ---------------- CSR build: count ----------------
__global__ __launch_bounds__(256) void k_count(const int* __restrict__ dst,
                                               int* __restrict__ cnt, int nE) {
  int e = blockIdx.x * 256 + threadIdx.x;
  if (e < nE) atomicAdd(&cnt[dst[e]], 1);
}

// ---------------- CSR build: exclusive scan (1 block per etype) ----------------
__global__ __launch_bounds__(1024) void k_scan(const int* c0, int* r0, int* u0, int n0,
                                               const int* c1, int* r1, int* u1, int n1,
                                               const int* c2, int* r2, int* u2, int n2) {
  const int* cnt = blockIdx.x == 0 ? c0 : (blockIdx.x == 1 ? c1 : c2);
  int* rs = blockIdx.x == 0 ? r0 : (blockIdx.x == 1 ? r1 : r2);
  int* cur = blockIdx.x == 0 ? u0 : (blockIdx.x == 1 ? u1 : u2);
  int n = blockIdx.x == 0 ? n0 : (blockIdx.x == 1 ? n1 : n2);

  __shared__ int sums[1024];
  int t = threadIdx.x;
  int chunk = (n + 1023) / 1024;
  int beg = t * chunk, end = min(beg + chunk, n);
  int s = 0;
  for (int i = beg; i < end; ++i) s += cnt[i];
  sums[t] = s;
  __syncthreads();
  for (int off = 1; off < 1024; off <<= 1) {
    int v = (t >= off) ? sums[t - off] : 0;
    __syncthreads();
    sums[t] += v;
    __syncthreads();
  }
  int run = (t == 0) ? 0 : sums[t - 1];
  for (int i = beg; i < end; ++i) {
    rs[i] = run;
    cur[i] = run;
    run += cnt[i];
  }
  if (beg < n && end == n) rs[n] = run;  // total
}

// ---------------- CSR build: fill ----------------
__global__ __launch_bounds__(256) void k_fill(const int* __restrict__ src,
                                              const int* __restrict__ dst,
                                              int* __restrict__ cursor,
                                              int* __restrict__ csr, int nE) {
  int e = blockIdx.x * 256 + threadIdx.x;
  if (e < nE) {
    int p = atomicAdd(&cursor[dst[e]], 1);
    csr[p] = src[e];
  }
}

// ---------------- mean aggregation: one wave per dst node ----------------
__global__ __launch_bounds__(256) void k_agg(const u16* __restrict__ h,
                                             const int* __restrict__ csr,
                                             const int* __restrict__ rs,
                                             u16* __restrict__ m, int n_dst) {
  int wid = blockIdx.x * 4 + (threadIdx.x >> 6);
  int lane = threadIdx.x & 63;
  if (wid >= n_dst) return;
  int e0 = rs[wid], e1 = rs[wid + 1];
  const f16x2* hp = (const f16x2*)h;
  float ax = 0.f, ay = 0.f;
  for (int e = e0; e < e1; ++e) {
    int s = csr[e];
    f16x2 v = hp[(size_t)s * 64 + lane];
    ax += (float)v[0];
    ay += (float)v[1];
  }
  float inv = (e1 > e0) ? 1.0f / (float)(e1 - e0) : 0.f;
  f16x2 r = {(f16)(ax * inv), (f16)(ay * inv)};
  ((f16x2*)m)[(size_t)wid * 64 + lane] = r;
}

// ---------------- fused GEMM: out = leaky( m@W (+ m2@W2) + masked biases ) ----------------
// Block 256 (4 waves), block tile M=128 (wave: 32 rows = 2 row-tiles), N=128, K=128.
template <int NE, int OUTF32>
__global__ __launch_bounds__(256) void k_gemm(
    const u16* __restrict__ mA, const u16* __restrict__ mBp,
    const float* __restrict__ WA, const float* __restrict__ WB,
    const float* __restrict__ bA, const float* __restrict__ bB,
    const int* __restrict__ cntA, const int* __restrict__ cntB,
    u16* __restrict__ o16, float* __restrict__ o32, int M) {
  __shared__ __align__(16) f16 Wt[NE][128][136];  // transposed W, +8 f16 pad
  int tid = threadIdx.x;
  for (int idx = tid; idx < 128 * 128; idx += 256) {
    int k = idx >> 7, n = idx & 127;
    Wt[0][n][k] = (f16)WA[idx];
    if (NE == 2) Wt[1][n][k] = (f16)WB[idx];
  }
  __syncthreads();

  int lane = tid & 63, w = tid >> 6;
  int lr = lane & 15;            // A row within tile / C col within tile
  int lk = (lane >> 4) * 8;      // K offset within 32-wide K step
  long row0 = (long)blockIdx.x * 128 + w * 32;

  f32x4 acc[2][8];
#pragma unroll
  for (int rt = 0; rt < 2; rt++)
#pragma unroll
    for (int n = 0; n < 8; n++) acc[rt][n] = (f32x4){0.f, 0.f, 0.f, 0.f};

#pragma unroll
  for (int e = 0; e < NE; ++e) {
    const f16* mm = (const f16*)((e == 0) ? mA : mBp);
#pragma unroll
    for (int ks = 0; ks < 4; ++ks) {
      int k0 = ks * 32 + lk;
      f16x8 bf[8];
#pragma unroll
      for (int n = 0; n < 8; n++) bf[n] = *(const f16x8*)&Wt[e][n * 16 + lr][k0];
#pragma unroll
      for (int rt = 0; rt < 2; rt++) {
        long r = row0 + rt * 16 + lr;
        if (r >= M) r = M - 1;  // clamped load; store is guarded
        f16x8 af = *(const f16x8*)(mm + r * D + k0);
#pragma unroll
        for (int n = 0; n < 8; n++)
          acc[rt][n] = __builtin_amdgcn_mfma_f32_16x16x32_f16(af, bf[n], acc[rt][n], 0, 0, 0);
      }
    }
  }

#pragma unroll
  for (int rt = 0; rt < 2; rt++) {
    long rbase = row0 + rt * 16 + (lane >> 4) * 4;
#pragma unroll
    for (int n = 0; n < 8; n++) {
      int col = n * 16 + lr;
      float biasA = bA[col];
      float biasB = (NE == 2) ? bB[col] : 0.f;
#pragma unroll
      for (int i = 0; i < 4; i++) {
        long r = rbase + i;
        if (r < M) {
          float v = acc[rt][n][i];
          if (cntA[r] > 0) v += biasA;
          if (NE == 2) {
            if (cntB[r] > 0) v += biasB;
          }
          v = v > 0.f ? v : 0.01f * v;
          if (OUTF32)
            o32[r * D + col] = v;
          else
            ((f16*)o16)[r * D + col] = (f16)v;
        }
      }
    }
  }
}

extern "C" void kernel_launch(void* const* d_in, const int* in_sizes, int n_in,
                              void* d_out, int out_size, void* d_ws, size_t ws_size,
                              hipStream_t stream) {
  const float* h_user = (const float*)d_in[0];
  const float* h_item = (const float*)d_in[1];
  const float* W = (const float*)d_in[2];
  const float* bb = (const float*)d_in[3];
  const int* f_src = (const int*)d_in[4];
  const int* f_dst = (const int*)d_in[5];
  const int* c_src = (const int*)d_in[6];
  const int* c_dst = (const int*)d_in[7];
  const int* cb_src = (const int*)d_in[8];
  const int* cb_dst = (const int*)d_in[9];

  const int NU = in_sizes[0] / D;
  const int NI = in_sizes[1] / D;
  const int nEf = in_sizes[4], nEc = in_sizes[6], nEcb = in_sizes[8];

  char* p = (char*)d_ws;
  auto alloc = [&](size_t bytes) {
    char* r = p;
    p += (bytes + 255) & ~(size_t)255;
    return r;
  };
  // counts (contiguous for single memset)
  int* cnt_f = (int*)alloc((size_t)NU * 4);
  int* cnt_c = (int*)alloc((size_t)NI * 4);
  int* cnt_cb = (int*)alloc((size_t)NU * 4);
  char* cnt_end = p;
  int* cur_f = (int*)alloc((size_t)NU * 4);
  int* cur_c = (int*)alloc((size_t)NI * 4);
  int* cur_cb = (int*)alloc((size_t)NU * 4);
  int* rs_f = (int*)alloc((size_t)(NU + 1) * 4);
  int* rs_c = (int*)alloc((size_t)(NI + 1) * 4);
  int* rs_cb = (int*)alloc((size_t)(NU + 1) * 4);
  int* csr_f = (int*)alloc((size_t)nEf * 4);
  int* csr_c = (int*)alloc((size_t)nEc * 4);
  int* csr_cb = (int*)alloc((size_t)nEcb * 4);
  u16* hu = (u16*)alloc((size_t)NU * D * 2);
  u16* hi = (u16*)alloc((size_t)NI * D * 2);
  u16* M0 = (u16*)alloc((size_t)(NU > NI ? NU : NI) * D * 2);
  u16* M1 = (u16*)alloc((size_t)NU * D * 2);
  (void)ws_size;  // ~109 MB required

  hipMemsetAsync(cnt_f, 0, (size_t)(cnt_end - (char*)cnt_f), stream);

  k_convert<<<(NU * D / 8 + 255) / 256, 256, 0, stream>>>(h_user, hu, NU * D / 8);
  k_convert<<<(NI * D / 8 + 255) / 256, 256, 0, stream>>>(h_item, hi, NI * D / 8);

  k_count<<<(nEf + 255) / 256, 256, 0, stream>>>(f_dst, cnt_f, nEf);
  k_count<<<(nEc + 255) / 256, 256, 0, stream>>>(c_dst, cnt_c, nEc);
  k_count<<<(nEcb + 255) / 256, 256, 0, stream>>>(cb_dst, cnt_cb, nEcb);

  k_scan<<<3, 1024, 0, stream>>>(cnt_f, rs_f, cur_f, NU,
                                 cnt_c, rs_c, cur_c, NI,
                                 cnt_cb, rs_cb, cur_cb, NU);

  k_fill<<<(nEf + 255) / 256, 256, 0, stream>>>(f_src, f_dst, cur_f, csr_f, nEf);
  k_fill<<<(nEc + 255) / 256, 256, 0, stream>>>(c_src, c_dst, cur_c, csr_c, nEc);
  k_fill<<<(nEcb + 255) / 256, 256, 0, stream>>>(cb_src, cb_dst, cur_cb, csr_cb, nEcb);

  float* out_u = (float*)d_out;
  float* out_i = (float*)d_out + (size_t)NU * D;

  for (int l = 0; l < 3; ++l) {
    const float* Wl = W + (size_t)l * 3 * D * D;
    const float* bl = bb + (size_t)l * 3 * D;

    // m_cb <- mean over cb edges of hi   [M1]
    k_agg<<<(NU + 3) / 4, 256, 0, stream>>>(hi, csr_cb, rs_cb, M1, NU);
    // m_c <- mean over clicks edges of hu  [M0]
    k_agg<<<(NI + 3) / 4, 256, 0, stream>>>(hu, csr_c, rs_c, M0, NI);

    // items: hi_next = leaky(m_c @ W[l][1] + mask*b[l][1])
    if (l < 2)
      k_gemm<1, 0><<<(NI + 127) / 128, 256, 0, stream>>>(
          M0, nullptr, Wl + D * D, nullptr, bl + D, nullptr, cnt_c, nullptr,
          hi, nullptr, NI);
    else
      k_gemm<1, 1><<<(NI + 127) / 128, 256, 0, stream>>>(
          M0, nullptr, Wl + D * D, nullptr, bl + D, nullptr, cnt_c, nullptr,
          nullptr, out_i, NI);

    // m_f <- mean over follows edges of hu  [M0 reuse, item GEMM already drained it]
    k_agg<<<(NU + 3) / 4, 256, 0, stream>>>(hu, csr_f, rs_f, M0, NU);

    // users: hu_next = leaky(m_f @ W[l][0] + m_cb @ W[l][2] + masked biases)
    if (l < 2)
      k_gemm<2, 0><<<(NU + 127) / 128, 256, 0, stream>>>(
          M0, M1, Wl, Wl + 2 * D * D, bl, bl + 2 * D, cnt_f, cnt_cb,
          hu, nullptr, NU);
    else
      k_gemm<2, 1><<<(NU + 127) / 128, 256, 0, stream>>>(
          M0, M1, Wl, Wl + 2 * D * D, bl, bl + 2 * D, cnt_f, cnt_cb,
          nullptr, out_u, NU);
  }
}

// Round 2
// 1103.793 us; speedup vs baseline: 1.1987x; 1.1987x over previous
//
#include <hip/hip_runtime.h>

typedef unsigned short u16;
typedef _Float16 f16;
typedef __attribute__((ext_vector_type(2))) _Float16 f16x2;
typedef __attribute__((ext_vector_type(8))) _Float16 f16x8;
typedef __attribute__((ext_vector_type(4))) float f32x4;

#define D 128

// ---------------- fp32 -> fp16 convert (8 elems/thread) ----------------
__global__ __launch_bounds__(256) void k_convert(const float* __restrict__ in,
                                                 u16* __restrict__ out, int n8) {
  int i = blockIdx.x * 256 + threadIdx.x;
  if (i >= n8) return;
  const float4* ip = (const float4*)in;
  float4 a = ip[i * 2], b = ip[i * 2 + 1];
  f16x8 v = {(f16)a.x, (f16)a.y, (f16)a.z, (f16)a.w,
             (f16)b.x, (f16)b.y, (f16)b.z, (f16)b.w};
  *(f16x8*)(out + (size_t)i * 8) = v;
}

// ---------------- CSR build: count ----------------
__global__ __launch_bounds__(256) void k_count(const int* __restrict__ dst,
                                               int* __restrict__ cnt, int nE) {
  int e = blockIdx.x * 256 + threadIdx.x;
  if (e < nE) atomicAdd(&cnt[dst[e]], 1);
}

// ---------------- device-wide exclusive scan, 3 passes ----------------
// Pass A: per-block (1024 elems) partial sums
__global__ __launch_bounds__(256) void k_scanA(const int* __restrict__ cnt,
                                               int* __restrict__ part, int n) {
  int t = threadIdx.x;
  int idx = blockIdx.x * 1024 + t * 4;
  int4 v = {0, 0, 0, 0};
  if (idx + 3 < n)
    v = *(const int4*)(cnt + idx);
  else {
    if (idx < n) v.x = cnt[idx];
    if (idx + 1 < n) v.y = cnt[idx + 1];
    if (idx + 2 < n) v.z = cnt[idx + 2];
    if (idx + 3 < n) v.w = cnt[idx + 3];
  }
  int s = v.x + v.y + v.z + v.w;
  for (int off = 1; off < 64; off <<= 1) s += __shfl_down(s, off, 64);
  __shared__ int ws[4];
  if ((t & 63) == 0) ws[t >> 6] = s;
  __syncthreads();
  if (t == 0) part[blockIdx.x] = ws[0] + ws[1] + ws[2] + ws[3];
}

// Pass B: single-block exclusive scan of partials (n_part <= 1024)
__global__ __launch_bounds__(1024) void k_scanB(int* __restrict__ part, int n_part) {
  __shared__ int sh[1024];
  int t = threadIdx.x;
  int v = (t < n_part) ? part[t] : 0;
  sh[t] = v;
  __syncthreads();
  for (int off = 1; off < 1024; off <<= 1) {
    int u = (t >= off) ? sh[t - off] : 0;
    __syncthreads();
    sh[t] += u;
    __syncthreads();
  }
  if (t < n_part) part[t] = sh[t] - v;  // exclusive
}

// Pass C: per-element exclusive prefix + block offset -> rs and cur
__global__ __launch_bounds__(256) void k_scanC(const int* __restrict__ cnt,
                                               const int* __restrict__ part,
                                               int* __restrict__ rs,
                                               int* __restrict__ cur,
                                               int n, int total) {
  int t = threadIdx.x;
  int idx = blockIdx.x * 1024 + t * 4;
  int4 v = {0, 0, 0, 0};
  if (idx + 3 < n)
    v = *(const int4*)(cnt + idx);
  else {
    if (idx < n) v.x = cnt[idx];
    if (idx + 1 < n) v.y = cnt[idx + 1];
    if (idx + 2 < n) v.z = cnt[idx + 2];
    if (idx + 3 < n) v.w = cnt[idx + 3];
  }
  int s = v.x + v.y + v.z + v.w;
  int inc = s;
  int lane = t & 63, w = t >> 6;
  for (int off = 1; off < 64; off <<= 1) {
    int u = __shfl_up(inc, off, 64);
    if (lane >= off) inc += u;
  }
  __shared__ int ws[4];
  if (lane == 63) ws[w] = inc;
  __syncthreads();
  int woff = 0;
  for (int i = 0; i < w; ++i) woff += ws[i];
  int ex = part[blockIdx.x] + woff + inc - s;
  int4 r;
  r.x = ex;
  r.y = ex + v.x;
  r.z = r.y + v.y;
  r.w = r.z + v.z;
  if (idx + 3 < n) {
    *(int4*)(rs + idx) = r;
    *(int4*)(cur + idx) = r;
  } else {
    if (idx < n) { rs[idx] = r.x; cur[idx] = r.x; }
    if (idx + 1 < n) { rs[idx + 1] = r.y; cur[idx + 1] = r.y; }
    if (idx + 2 < n) { rs[idx + 2] = r.z; cur[idx + 2] = r.z; }
    if (idx + 3 < n) { rs[idx + 3] = r.w; cur[idx + 3] = r.w; }
  }
  if (blockIdx.x == 0 && t == 0) rs[n] = total;
}

// ---------------- CSR build: fill ----------------
__global__ __launch_bounds__(256) void k_fill(const int* __restrict__ src,
                                              const int* __restrict__ dst,
                                              int* __restrict__ cursor,
                                              int* __restrict__ csr, int nE) {
  int e = blockIdx.x * 256 + threadIdx.x;
  if (e < nE) {
    int p = atomicAdd(&cursor[dst[e]], 1);
    csr[p] = src[e];
  }
}

// ---------------- mean aggregation: one wave per dst node ----------------
__global__ __launch_bounds__(256) void k_agg(const u16* __restrict__ h,
                                             const int* __restrict__ csr,
                                             const int* __restrict__ rs,
                                             u16* __restrict__ m, int n_dst) {
  int wid = blockIdx.x * 4 + (threadIdx.x >> 6);
  int lane = threadIdx.x & 63;
  if (wid >= n_dst) return;
  int e0 = rs[wid], e1 = rs[wid + 1];
  const f16x2* hp = (const f16x2*)h;
  float ax = 0.f, ay = 0.f;
  for (int e = e0; e < e1; ++e) {
    int s = csr[e];
    f16x2 v = hp[(size_t)s * 64 + lane];
    ax += (float)v[0];
    ay += (float)v[1];
  }
  float inv = (e1 > e0) ? 1.0f / (float)(e1 - e0) : 0.f;
  f16x2 r = {(f16)(ax * inv), (f16)(ay * inv)};
  ((f16x2*)m)[(size_t)wid * 64 + lane] = r;
}

// ---------------- fused GEMM: out = leaky( m@W (+ m2@W2) + masked biases ) ----------------
template <int NE, int OUTF32>
__global__ __launch_bounds__(256) void k_gemm(
    const u16* __restrict__ mA, const u16* __restrict__ mBp,
    const float* __restrict__ WA, const float* __restrict__ WB,
    const float* __restrict__ bA, const float* __restrict__ bB,
    const int* __restrict__ cntA, const int* __restrict__ cntB,
    u16* __restrict__ o16, float* __restrict__ o32, int M) {
  __shared__ __align__(16) f16 Wt[NE][128][136];  // transposed W, +8 f16 pad
  int tid = threadIdx.x;
  for (int idx = tid; idx < 128 * 128; idx += 256) {
    int k = idx >> 7, n = idx & 127;
    Wt[0][n][k] = (f16)WA[idx];
    if (NE == 2) Wt[1][n][k] = (f16)WB[idx];
  }
  __syncthreads();

  int lane = tid & 63, w = tid >> 6;
  int lr = lane & 15;        // A row within tile / C col within tile
  int lk = (lane >> 4) * 8;  // K offset within 32-wide K step
  long row0 = (long)blockIdx.x * 128 + w * 32;

  f32x4 acc[2][8];
#pragma unroll
  for (int rt = 0; rt < 2; rt++)
#pragma unroll
    for (int n = 0; n < 8; n++) acc[rt][n] = (f32x4){0.f, 0.f, 0.f, 0.f};

#pragma unroll
  for (int e = 0; e < NE; ++e) {
    const f16* mm = (const f16*)((e == 0) ? mA : mBp);
#pragma unroll
    for (int ks = 0; ks < 4; ++ks) {
      int k0 = ks * 32 + lk;
      f16x8 bf[8];
#pragma unroll
      for (int n = 0; n < 8; n++) bf[n] = *(const f16x8*)&Wt[e][n * 16 + lr][k0];
#pragma unroll
      for (int rt = 0; rt < 2; rt++) {
        long r = row0 + rt * 16 + lr;
        if (r >= M) r = M - 1;  // clamped load; store is guarded
        f16x8 af = *(const f16x8*)(mm + r * D + k0);
#pragma unroll
        for (int n = 0; n < 8; n++)
          acc[rt][n] = __builtin_amdgcn_mfma_f32_16x16x32_f16(af, bf[n], acc[rt][n], 0, 0, 0);
      }
    }
  }

#pragma unroll
  for (int rt = 0; rt < 2; rt++) {
    long rbase = row0 + rt * 16 + (lane >> 4) * 4;
#pragma unroll
    for (int n = 0; n < 8; n++) {
      int col = n * 16 + lr;
      float biasA = bA[col];
      float biasB = (NE == 2) ? bB[col] : 0.f;
#pragma unroll
      for (int i = 0; i < 4; i++) {
        long r = rbase + i;
        if (r < M) {
          float v = acc[rt][n][i];
          if (cntA[r] > 0) v += biasA;
          if (NE == 2) {
            if (cntB[r] > 0) v += biasB;
          }
          v = v > 0.f ? v : 0.01f * v;
          if (OUTF32)
            o32[r * D + col] = v;
          else
            ((f16*)o16)[r * D + col] = (f16)v;
        }
      }
    }
  }
}

extern "C" void kernel_launch(void* const* d_in, const int* in_sizes, int n_in,
                              void* d_out, int out_size, void* d_ws, size_t ws_size,
                              hipStream_t stream) {
  const float* h_user = (const float*)d_in[0];
  const float* h_item = (const float*)d_in[1];
  const float* W = (const float*)d_in[2];
  const float* bb = (const float*)d_in[3];
  const int* f_src = (const int*)d_in[4];
  const int* f_dst = (const int*)d_in[5];
  const int* c_src = (const int*)d_in[6];
  const int* c_dst = (const int*)d_in[7];
  const int* cb_src = (const int*)d_in[8];
  const int* cb_dst = (const int*)d_in[9];

  const int NU = in_sizes[0] / D;
  const int NI = in_sizes[1] / D;
  const int nEf = in_sizes[4], nEc = in_sizes[6], nEcb = in_sizes[8];
  const int N3 = NU + NI + NU;               // concatenated node-count space
  const int nE = nEf + nEc + nEcb;           // concatenated edge space

  char* p = (char*)d_ws;
  auto alloc = [&](size_t bytes) {
    char* r = p;
    p += (bytes + 255) & ~(size_t)255;
    return r;
  };
  int* cnt_all = (int*)alloc((size_t)N3 * 4);     // [cnt_f | cnt_c | cnt_cb]
  int* cur_all = (int*)alloc((size_t)N3 * 4);
  int* rs_all = (int*)alloc((size_t)(N3 + 1) * 4);
  int* part = (int*)alloc(1024 * 4);
  int* csr_all = (int*)alloc((size_t)nE * 4);     // [csr_f | csr_c | csr_cb]
  u16* hu = (u16*)alloc((size_t)NU * D * 2);
  u16* hi = (u16*)alloc((size_t)NI * D * 2);
  u16* M0 = (u16*)alloc((size_t)(NU > NI ? NU : NI) * D * 2);
  u16* M1 = (u16*)alloc((size_t)NU * D * 2);
  (void)ws_size;

  int* cnt_f = cnt_all;
  int* cnt_c = cnt_all + NU;
  int* cnt_cb = cnt_all + NU + NI;
  int* cur_f = cur_all;
  int* cur_c = cur_all + NU;
  int* cur_cb = cur_all + NU + NI;
  int* rs_f = rs_all;
  int* rs_c = rs_all + NU;
  int* rs_cb = rs_all + NU + NI;

  hipMemsetAsync(cnt_all, 0, (size_t)N3 * 4, stream);

  k_convert<<<(NU * D / 8 + 255) / 256, 256, 0, stream>>>(h_user, hu, NU * D / 8);
  k_convert<<<(NI * D / 8 + 255) / 256, 256, 0, stream>>>(h_item, hi, NI * D / 8);

  k_count<<<(nEf + 255) / 256, 256, 0, stream>>>(f_dst, cnt_f, nEf);
  k_count<<<(nEc + 255) / 256, 256, 0, stream>>>(c_dst, cnt_c, nEc);
  k_count<<<(nEcb + 255) / 256, 256, 0, stream>>>(cb_dst, cnt_cb, nEcb);

  int n_part = (N3 + 1023) / 1024;
  k_scanA<<<n_part, 256, 0, stream>>>(cnt_all, part, N3);
  k_scanB<<<1, 1024, 0, stream>>>(part, n_part);
  k_scanC<<<n_part, 256, 0, stream>>>(cnt_all, part, rs_all, cur_all, N3, nE);

  k_fill<<<(nEf + 255) / 256, 256, 0, stream>>>(f_src, f_dst, cur_f, csr_all, nEf);
  k_fill<<<(nEc + 255) / 256, 256, 0, stream>>>(c_src, c_dst, cur_c, csr_all, nEc);
  k_fill<<<(nEcb + 255) / 256, 256, 0, stream>>>(cb_src, cb_dst, cur_cb, csr_all, nEcb);

  float* out_u = (float*)d_out;
  float* out_i = (float*)d_out + (size_t)NU * D;

  for (int l = 0; l < 3; ++l) {
    const float* Wl = W + (size_t)l * 3 * D * D;
    const float* bl = bb + (size_t)l * 3 * D;

    // m_cb <- mean over cb edges of hi   [M1]
    k_agg<<<(NU + 3) / 4, 256, 0, stream>>>(hi, csr_all, rs_cb, M1, NU);
    // m_c <- mean over clicks edges of hu  [M0]
    k_agg<<<(NI + 3) / 4, 256, 0, stream>>>(hu, csr_all, rs_c, M0, NI);

    // items: hi_next = leaky(m_c @ W[l][1] + mask*b[l][1])
    if (l < 2)
      k_gemm<1, 0><<<(NI + 127) / 128, 256, 0, stream>>>(
          M0, nullptr, Wl + D * D, nullptr, bl + D, nullptr, cnt_c, nullptr,
          hi, nullptr, NI);
    else
      k_gemm<1, 1><<<(NI + 127) / 128, 256, 0, stream>>>(
          M0, nullptr, Wl + D * D, nullptr, bl + D, nullptr, cnt_c, nullptr,
          nullptr, out_i, NI);

    // m_f <- mean over follows edges of hu  [M0 reuse, item GEMM already drained it]
    k_agg<<<(NU + 3) / 4, 256, 0, stream>>>(hu, csr_all, rs_f, M0, NU);

    // users: hu_next = leaky(m_f @ W[l][0] + m_cb @ W[l][2] + masked biases)
    if (l < 2)
      k_gemm<2, 0><<<(NU + 127) / 128, 256, 0, stream>>>(
          M0, M1, Wl, Wl + 2 * D * D, bl, bl + 2 * D, cnt_f, cnt_cb,
          hu, nullptr, NU);
    else
      k_gemm<2, 1><<<(NU + 127) / 128, 256, 0, stream>>>(
          M0, M1, Wl, Wl + 2 * D * D, bl, bl + 2 * D, cnt_f, cnt_cb,
          nullptr, out_u, NU);
  }
}

// Round 3
// 747.410 us; speedup vs baseline: 1.7702x; 1.4768x over previous
//
#include <hip/hip_runtime.h>

typedef unsigned short u16;
typedef _Float16 f16;
typedef __attribute__((ext_vector_type(2))) _Float16 f16x2;
typedef __attribute__((ext_vector_type(8))) _Float16 f16x8;
typedef __attribute__((ext_vector_type(4))) float f32x4;

#define D 128

// ---------------- fp32 -> fp16 convert (8 elems/thread) ----------------
__global__ __launch_bounds__(256) void k_convert(const float* __restrict__ in,
                                                 u16* __restrict__ out, int n8) {
  int i = blockIdx.x * 256 + threadIdx.x;
  if (i >= n8) return;
  const float4* ip = (const float4*)in;
  float4 a = ip[i * 2], b = ip[i * 2 + 1];
  f16x8 v = {(f16)a.x, (f16)a.y, (f16)a.z, (f16)a.w,
             (f16)b.x, (f16)b.y, (f16)b.z, (f16)b.w};
  *(f16x8*)(out + (size_t)i * 8) = v;
}

// ---------------- W (9 x 128 x 128 fp32) -> fp16 transposed ----------------
__global__ __launch_bounds__(256) void k_convW(const float* __restrict__ W,
                                               u16* __restrict__ Wt, int total) {
  int idx = blockIdx.x * 256 + threadIdx.x;
  if (idx >= total) return;
  int mat = idx >> 14;
  int k = (idx >> 7) & 127;
  int n = idx & 127;
  f16 v = (f16)W[idx];
  ((f16*)Wt)[(size_t)mat * 16384 + n * 128 + k] = v;
}

// ---------------- CSR build: count ----------------
__global__ __launch_bounds__(256) void k_count(const int* __restrict__ dst,
                                               int* __restrict__ cnt, int nE) {
  int e = blockIdx.x * 256 + threadIdx.x;
  if (e < nE) atomicAdd(&cnt[dst[e]], 1);
}

// ---------------- device-wide exclusive scan, 3 passes ----------------
__global__ __launch_bounds__(256) void k_scanA(const int* __restrict__ cnt,
                                               int* __restrict__ part, int n) {
  int t = threadIdx.x;
  int idx = blockIdx.x * 1024 + t * 4;
  int4 v = {0, 0, 0, 0};
  if (idx + 3 < n)
    v = *(const int4*)(cnt + idx);
  else {
    if (idx < n) v.x = cnt[idx];
    if (idx + 1 < n) v.y = cnt[idx + 1];
    if (idx + 2 < n) v.z = cnt[idx + 2];
    if (idx + 3 < n) v.w = cnt[idx + 3];
  }
  int s = v.x + v.y + v.z + v.w;
  for (int off = 1; off < 64; off <<= 1) s += __shfl_down(s, off, 64);
  __shared__ int ws[4];
  if ((t & 63) == 0) ws[t >> 6] = s;
  __syncthreads();
  if (t == 0) part[blockIdx.x] = ws[0] + ws[1] + ws[2] + ws[3];
}

__global__ __launch_bounds__(1024) void k_scanB(int* __restrict__ part, int n_part) {
  __shared__ int sh[1024];
  int t = threadIdx.x;
  int v = (t < n_part) ? part[t] : 0;
  sh[t] = v;
  __syncthreads();
  for (int off = 1; off < 1024; off <<= 1) {
    int u = (t >= off) ? sh[t - off] : 0;
    __syncthreads();
    sh[t] += u;
    __syncthreads();
  }
  if (t < n_part) part[t] = sh[t] - v;  // exclusive
}

__global__ __launch_bounds__(256) void k_scanC(const int* __restrict__ cnt,
                                               const int* __restrict__ part,
                                               int* __restrict__ rs,
                                               int* __restrict__ cur,
                                               int n, int total) {
  int t = threadIdx.x;
  int idx = blockIdx.x * 1024 + t * 4;
  int4 v = {0, 0, 0, 0};
  if (idx + 3 < n)
    v = *(const int4*)(cnt + idx);
  else {
    if (idx < n) v.x = cnt[idx];
    if (idx + 1 < n) v.y = cnt[idx + 1];
    if (idx + 2 < n) v.z = cnt[idx + 2];
    if (idx + 3 < n) v.w = cnt[idx + 3];
  }
  int s = v.x + v.y + v.z + v.w;
  int inc = s;
  int lane = t & 63, w = t >> 6;
  for (int off = 1; off < 64; off <<= 1) {
    int u = __shfl_up(inc, off, 64);
    if (lane >= off) inc += u;
  }
  __shared__ int ws[4];
  if (lane == 63) ws[w] = inc;
  __syncthreads();
  int woff = 0;
  for (int i = 0; i < w; ++i) woff += ws[i];
  int ex = part[blockIdx.x] + woff + inc - s;
  int4 r;
  r.x = ex;
  r.y = ex + v.x;
  r.z = r.y + v.y;
  r.w = r.z + v.z;
  if (idx + 3 < n) {
    *(int4*)(rs + idx) = r;
    *(int4*)(cur + idx) = r;
  } else {
    if (idx < n) { rs[idx] = r.x; cur[idx] = r.x; }
    if (idx + 1 < n) { rs[idx + 1] = r.y; cur[idx + 1] = r.y; }
    if (idx + 2 < n) { rs[idx + 2] = r.z; cur[idx + 2] = r.z; }
    if (idx + 3 < n) { rs[idx + 3] = r.w; cur[idx + 3] = r.w; }
  }
  if (blockIdx.x == 0 && t == 0) rs[n] = total;
}

// ---------------- CSR build: fill ----------------
__global__ __launch_bounds__(256) void k_fill(const int* __restrict__ src,
                                              const int* __restrict__ dst,
                                              int* __restrict__ cursor,
                                              int* __restrict__ csr, int nE) {
  int e = blockIdx.x * 256 + threadIdx.x;
  if (e < nE) {
    int p = atomicAdd(&cursor[dst[e]], 1);
    csr[p] = src[e];
  }
}

// ---------------- mean aggregation: 4 nodes per wave (4-deep MLP) ----------------
// Global node space w in [0, 2*NU+NI): [0,NU)=follows(src hu)->Mf,
// [NU,NU+NI)=clicks(src hu)->Mc, [NU+NI,..)=cb(src hi)->Mcb.
__global__ __launch_bounds__(256) void k_agg3(
    const u16* __restrict__ hu_, const u16* __restrict__ hi_,
    const int* __restrict__ csr, const int* __restrict__ rs,
    u16* __restrict__ Mf, u16* __restrict__ Mc, u16* __restrict__ Mcb,
    int NU, int NI, int wbeg, int wcnt) {
  int wave = (blockIdx.x * 256 + threadIdx.x) >> 6;
  int lane = threadIdx.x & 63;
  int base = wbeg + wave * 4;
  int wend = wbeg + wcnt;

#define NODE_INIT(K)                                                         \
  int w##K = base + K;                                                       \
  bool val##K = (w##K < wend);                                               \
  int e##K = val##K ? rs[w##K] : 0;                                          \
  int en##K = val##K ? rs[w##K + 1] : 0;                                     \
  const f16x2* tab##K;                                                       \
  f16x2* out##K;                                                             \
  {                                                                          \
    int wc = val##K ? w##K : 0;                                              \
    if (wc < NU) {                                                           \
      tab##K = (const f16x2*)hu_;                                            \
      out##K = (f16x2*)Mf + (size_t)wc * 64;                                 \
    } else if (wc < NU + NI) {                                               \
      tab##K = (const f16x2*)hu_;                                            \
      out##K = (f16x2*)Mc + (size_t)(wc - NU) * 64;                          \
    } else {                                                                 \
      tab##K = (const f16x2*)hi_;                                            \
      out##K = (f16x2*)Mcb + (size_t)(wc - NU - NI) * 64;                    \
    }                                                                        \
  }                                                                          \
  float ax##K = 0.f, ay##K = 0.f;                                            \
  int deg##K = en##K - e##K;

  NODE_INIT(0)
  NODE_INIT(1)
  NODE_INIT(2)
  NODE_INIT(3)
#undef NODE_INIT

  while (true) {
    bool a0 = e0 < en0, a1 = e1 < en1, a2 = e2 < en2, a3 = e3 < en3;
    if (!(a0 | a1 | a2 | a3)) break;
    int s0 = csr[a0 ? e0 : 0];
    int s1 = csr[a1 ? e1 : 0];
    int s2 = csr[a2 ? e2 : 0];
    int s3 = csr[a3 ? e3 : 0];
    f16x2 v0 = {0, 0}, v1 = {0, 0}, v2 = {0, 0}, v3 = {0, 0};
    if (a0) v0 = tab0[(size_t)s0 * 64 + lane];
    if (a1) v1 = tab1[(size_t)s1 * 64 + lane];
    if (a2) v2 = tab2[(size_t)s2 * 64 + lane];
    if (a3) v3 = tab3[(size_t)s3 * 64 + lane];
    if (a0) { ax0 += (float)v0[0]; ay0 += (float)v0[1]; e0++; }
    if (a1) { ax1 += (float)v1[0]; ay1 += (float)v1[1]; e1++; }
    if (a2) { ax2 += (float)v2[0]; ay2 += (float)v2[1]; e2++; }
    if (a3) { ax3 += (float)v3[0]; ay3 += (float)v3[1]; e3++; }
  }

#define NODE_OUT(K)                                                          \
  if (val##K) {                                                              \
    float inv = deg##K ? 1.0f / (float)deg##K : 0.f;                         \
    out##K[lane] = (f16x2){(f16)(ax##K * inv), (f16)(ay##K * inv)};          \
  }
  NODE_OUT(0)
  NODE_OUT(1)
  NODE_OUT(2)
  NODE_OUT(3)
#undef NODE_OUT
}

// ---------------- fused GEMM: out = leaky( m@W (+ m2@W2) + masked biases ) ----------------
template <int NE, int OUTF32>
__global__ __launch_bounds__(256) void k_gemm(
    const u16* __restrict__ mA, const u16* __restrict__ mBp,
    const u16* __restrict__ wtA, const u16* __restrict__ wtB,  // fp16, transposed [n][k]
    const float* __restrict__ bA, const float* __restrict__ bB,
    const int* __restrict__ rsA, const int* __restrict__ rsB,
    u16* __restrict__ o16, float* __restrict__ o32, int M) {
  __shared__ __align__(16) f16 Wt[NE][128][136];  // +8 f16 pad
  int tid = threadIdx.x;
  {
    const f16x8* wa = (const f16x8*)wtA;
    for (int idx = tid; idx < 128 * 16; idx += 256) {
      int n = idx >> 4, c = idx & 15;
      *(f16x8*)&Wt[0][n][c * 8] = wa[idx];
    }
    if (NE == 2) {
      const f16x8* wb = (const f16x8*)wtB;
      for (int idx = tid; idx < 128 * 16; idx += 256) {
        int n = idx >> 4, c = idx & 15;
        *(f16x8*)&Wt[1][n][c * 8] = wb[idx];
      }
    }
  }
  __syncthreads();

  int lane = tid & 63, w = tid >> 6;
  int lr = lane & 15;        // A row within tile / C col within tile
  int lk = (lane >> 4) * 8;  // K offset within 32-wide K step
  long row0 = (long)blockIdx.x * 128 + w * 32;

  f32x4 acc[2][8];
#pragma unroll
  for (int rt = 0; rt < 2; rt++)
#pragma unroll
    for (int n = 0; n < 8; n++) acc[rt][n] = (f32x4){0.f, 0.f, 0.f, 0.f};

#pragma unroll
  for (int e = 0; e < NE; ++e) {
    const f16* mm = (const f16*)((e == 0) ? mA : mBp);
#pragma unroll
    for (int ks = 0; ks < 4; ++ks) {
      int k0 = ks * 32 + lk;
      f16x8 bf[8];
#pragma unroll
      for (int n = 0; n < 8; n++) bf[n] = *(const f16x8*)&Wt[e][n * 16 + lr][k0];
#pragma unroll
      for (int rt = 0; rt < 2; rt++) {
        long r = row0 + rt * 16 + lr;
        if (r >= M) r = M - 1;  // clamped load; store is guarded
        f16x8 af = *(const f16x8*)(mm + r * D + k0);
#pragma unroll
        for (int n = 0; n < 8; n++)
          acc[rt][n] = __builtin_amdgcn_mfma_f32_16x16x32_f16(af, bf[n], acc[rt][n], 0, 0, 0);
      }
    }
  }

  // biases for this lane's 8 columns
  float bAr[8], bBr[8];
#pragma unroll
  for (int n = 0; n < 8; n++) {
    bAr[n] = bA[n * 16 + lr];
    bBr[n] = (NE == 2) ? bB[n * 16 + lr] : 0.f;
  }

#pragma unroll
  for (int rt = 0; rt < 2; rt++) {
    long rbase = row0 + rt * 16 + (lane >> 4) * 4;
#pragma unroll
    for (int i = 0; i < 4; i++) {
      long r = rbase + i;
      if (r < M) {
        bool mAok = rsA[r + 1] > rsA[r];
        bool mBok = (NE == 2) && (rsB[r + 1] > rsB[r]);
#pragma unroll
        for (int n = 0; n < 8; n++) {
          int col = n * 16 + lr;
          float v = acc[rt][n][i];
          if (mAok) v += bAr[n];
          if (mBok) v += bBr[n];
          v = v > 0.f ? v : 0.01f * v;
          if (OUTF32)
            o32[r * D + col] = v;
          else
            ((f16*)o16)[r * D + col] = (f16)v;
        }
      }
    }
  }
}

extern "C" void kernel_launch(void* const* d_in, const int* in_sizes, int n_in,
                              void* d_out, int out_size, void* d_ws, size_t ws_size,
                              hipStream_t stream) {
  const float* h_user = (const float*)d_in[0];
  const float* h_item = (const float*)d_in[1];
  const float* W = (const float*)d_in[2];
  const float* bb = (const float*)d_in[3];
  const int* f_src = (const int*)d_in[4];
  const int* f_dst = (const int*)d_in[5];
  const int* c_src = (const int*)d_in[6];
  const int* c_dst = (const int*)d_in[7];
  const int* cb_src = (const int*)d_in[8];
  const int* cb_dst = (const int*)d_in[9];

  const int NU = in_sizes[0] / D;
  const int NI = in_sizes[1] / D;
  const int nEf = in_sizes[4], nEc = in_sizes[6], nEcb = in_sizes[8];
  const int N3 = NU + NI + NU;     // concatenated node-count space
  const int nE = nEf + nEc + nEcb; // concatenated edge space

  char* p = (char*)d_ws;
  auto alloc = [&](size_t bytes) {
    char* r = p;
    p += (bytes + 255) & ~(size_t)255;
    return r;
  };
  int* cnt_all = (int*)alloc((size_t)N3 * 4);
  int* cur_all = (int*)alloc((size_t)N3 * 4);
  int* rs_all = (int*)alloc((size_t)(N3 + 1) * 4);
  int* part = (int*)alloc(1024 * 4);
  u16* Wtg = (u16*)alloc((size_t)9 * 16384 * 2);
  int* csr_all = (int*)alloc((size_t)nE * 4);
  int maxN = NU > NI ? NU : NI;
  u16* hu = (u16*)alloc((size_t)NU * D * 2);
  u16* hi = (u16*)alloc((size_t)NI * D * 2);
  u16* M0 = (u16*)alloc((size_t)maxN * D * 2);  // Mf (fused) / shared (fallback)
  u16* M1 = (u16*)alloc((size_t)NU * D * 2);    // Mcb
  size_t used_base = (size_t)(p - (char*)d_ws);
  size_t need_M2 = (size_t)NI * D * 2;
  bool fused = (used_base + need_M2 + 256 <= ws_size);
  u16* M2 = fused ? (u16*)alloc(need_M2) : M0;  // Mc

  int* cur_f = cur_all;
  int* cur_c = cur_all + NU;
  int* cur_cb = cur_all + NU + NI;
  int* rs_f = rs_all;
  int* rs_c = rs_all + NU;
  int* rs_cb = rs_all + NU + NI;

  hipMemsetAsync(cnt_all, 0, (size_t)N3 * 4, stream);

  k_convert<<<(NU * D / 8 + 255) / 256, 256, 0, stream>>>(h_user, hu, NU * D / 8);
  k_convert<<<(NI * D / 8 + 255) / 256, 256, 0, stream>>>(h_item, hi, NI * D / 8);
  k_convW<<<(9 * 16384 + 255) / 256, 256, 0, stream>>>(W, Wtg, 9 * 16384);

  k_count<<<(nEf + 255) / 256, 256, 0, stream>>>(f_dst, cnt_all, nEf);
  k_count<<<(nEc + 255) / 256, 256, 0, stream>>>(c_dst, cnt_all + NU, nEc);
  k_count<<<(nEcb + 255) / 256, 256, 0, stream>>>(cb_dst, cnt_all + NU + NI, nEcb);

  int n_part = (N3 + 1023) / 1024;
  k_scanA<<<n_part, 256, 0, stream>>>(cnt_all, part, N3);
  k_scanB<<<1, 1024, 0, stream>>>(part, n_part);
  k_scanC<<<n_part, 256, 0, stream>>>(cnt_all, part, rs_all, cur_all, N3, nE);

  k_fill<<<(nEf + 255) / 256, 256, 0, stream>>>(f_src, f_dst, cur_f, csr_all, nEf);
  k_fill<<<(nEc + 255) / 256, 256, 0, stream>>>(c_src, c_dst, cur_c, csr_all, nEc);
  k_fill<<<(nEcb + 255) / 256, 256, 0, stream>>>(cb_src, cb_dst, cur_cb, csr_all, nEcb);

  float* out_u = (float*)d_out;
  float* out_i = (float*)d_out + (size_t)NU * D;

  auto agg_launch = [&](int wbeg, int wcnt) {
    int waves = (wcnt + 3) / 4;
    int blocks = (waves + 3) / 4;
    k_agg3<<<blocks, 256, 0, stream>>>(hu, hi, csr_all, rs_all, M0, M2, M1,
                                       NU, NI, wbeg, wcnt);
  };

  for (int l = 0; l < 3; ++l) {
    const u16* Wl = Wtg + (size_t)l * 3 * 16384;
    const float* bl = bb + (size_t)l * 3 * D;

    if (fused) {
      agg_launch(0, N3);  // Mf=M0, Mc=M2, Mcb=M1
    } else {
      agg_launch(NU + NI, NU);  // cb -> M1
      agg_launch(NU, NI);       // clicks -> M2 (=M0)
    }

    // items: hi_next = leaky(Mc @ W[l][1] + mask*b[l][1])
    if (l < 2)
      k_gemm<1, 0><<<(NI + 127) / 128, 256, 0, stream>>>(
          M2, nullptr, Wl + 16384, nullptr, bl + D, nullptr, rs_c, nullptr,
          hi, nullptr, NI);
    else
      k_gemm<1, 1><<<(NI + 127) / 128, 256, 0, stream>>>(
          M2, nullptr, Wl + 16384, nullptr, bl + D, nullptr, rs_c, nullptr,
          nullptr, out_i, NI);

    if (!fused) agg_launch(0, NU);  // follows -> M0

    // users: hu_next = leaky(Mf @ W[l][0] + Mcb @ W[l][2] + masked biases)
    if (l < 2)
      k_gemm<2, 0><<<(NU + 127) / 128, 256, 0, stream>>>(
          M0, M1, Wl, Wl + 2 * 16384, bl, bl + 2 * D, rs_f, rs_cb,
          hu, nullptr, NU);
    else
      k_gemm<2, 1><<<(NU + 127) / 128, 256, 0, stream>>>(
          M0, M1, Wl, Wl + 2 * 16384, bl, bl + 2 * D, rs_f, rs_cb,
          nullptr, out_u, NU);
  }
}

// Round 4
// 586.608 us; speedup vs baseline: 2.2554x; 1.2741x over previous
//
#include <hip/hip_runtime.h>

typedef unsigned short u16;
typedef _Float16 f16;
typedef __attribute__((ext_vector_type(2))) _Float16 f16x2;
typedef __attribute__((ext_vector_type(8))) _Float16 f16x8;
typedef __attribute__((ext_vector_type(2))) float f32x2;
typedef __attribute__((ext_vector_type(4))) float f32x4;

#define D 128

// ---------------- fp32 -> fp16 convert (8 elems/thread) ----------------
__global__ __launch_bounds__(256) void k_convert(const float* __restrict__ in,
                                                 u16* __restrict__ out, int n8) {
  int i = blockIdx.x * 256 + threadIdx.x;
  if (i >= n8) return;
  const float4* ip = (const float4*)in;
  float4 a = ip[i * 2], b = ip[i * 2 + 1];
  f16x8 v = {(f16)a.x, (f16)a.y, (f16)a.z, (f16)a.w,
             (f16)b.x, (f16)b.y, (f16)b.z, (f16)b.w};
  *(f16x8*)(out + (size_t)i * 8) = v;
}

// ---------------- W (9 x 128 x 128 fp32) -> fp16 transposed ----------------
__global__ __launch_bounds__(256) void k_convW(const float* __restrict__ W,
                                               u16* __restrict__ Wt, int total) {
  int idx = blockIdx.x * 256 + threadIdx.x;
  if (idx >= total) return;
  int mat = idx >> 14;
  int k = (idx >> 7) & 127;
  int n = idx & 127;
  f16 v = (f16)W[idx];
  ((f16*)Wt)[(size_t)mat * 16384 + n * 128 + k] = v;
}

// ---------------- CSR build: count ----------------
__global__ __launch_bounds__(256) void k_count(const int* __restrict__ dst,
                                               int* __restrict__ cnt, int nE) {
  int e = blockIdx.x * 256 + threadIdx.x;
  if (e < nE) atomicAdd(&cnt[dst[e]], 1);
}

// ---------------- device-wide exclusive scan, 3 passes ----------------
__global__ __launch_bounds__(256) void k_scanA(const int* __restrict__ cnt,
                                               int* __restrict__ part, int n) {
  int t = threadIdx.x;
  int idx = blockIdx.x * 1024 + t * 4;
  int4 v = {0, 0, 0, 0};
  if (idx + 3 < n)
    v = *(const int4*)(cnt + idx);
  else {
    if (idx < n) v.x = cnt[idx];
    if (idx + 1 < n) v.y = cnt[idx + 1];
    if (idx + 2 < n) v.z = cnt[idx + 2];
    if (idx + 3 < n) v.w = cnt[idx + 3];
  }
  int s = v.x + v.y + v.z + v.w;
  for (int off = 1; off < 64; off <<= 1) s += __shfl_down(s, off, 64);
  __shared__ int ws[4];
  if ((t & 63) == 0) ws[t >> 6] = s;
  __syncthreads();
  if (t == 0) part[blockIdx.x] = ws[0] + ws[1] + ws[2] + ws[3];
}

__global__ __launch_bounds__(1024) void k_scanB(int* __restrict__ part, int n_part) {
  __shared__ int sh[1024];
  int t = threadIdx.x;
  int v = (t < n_part) ? part[t] : 0;
  sh[t] = v;
  __syncthreads();
  for (int off = 1; off < 1024; off <<= 1) {
    int u = (t >= off) ? sh[t - off] : 0;
    __syncthreads();
    sh[t] += u;
    __syncthreads();
  }
  if (t < n_part) part[t] = sh[t] - v;  // exclusive
}

__global__ __launch_bounds__(256) void k_scanC(const int* __restrict__ cnt,
                                               const int* __restrict__ part,
                                               int* __restrict__ rs,
                                               int n, int total) {
  int t = threadIdx.x;
  int idx = blockIdx.x * 1024 + t * 4;
  int4 v = {0, 0, 0, 0};
  if (idx + 3 < n)
    v = *(const int4*)(cnt + idx);
  else {
    if (idx < n) v.x = cnt[idx];
    if (idx + 1 < n) v.y = cnt[idx + 1];
    if (idx + 2 < n) v.z = cnt[idx + 2];
    if (idx + 3 < n) v.w = cnt[idx + 3];
  }
  int s = v.x + v.y + v.z + v.w;
  int inc = s;
  int lane = t & 63, w = t >> 6;
  for (int off = 1; off < 64; off <<= 1) {
    int u = __shfl_up(inc, off, 64);
    if (lane >= off) inc += u;
  }
  __shared__ int ws[4];
  if (lane == 63) ws[w] = inc;
  __syncthreads();
  int woff = 0;
  for (int i = 0; i < w; ++i) woff += ws[i];
  int ex = part[blockIdx.x] + woff + inc - s;
  int4 r;
  r.x = ex;
  r.y = ex + v.x;
  r.z = r.y + v.y;
  r.w = r.z + v.z;
  if (idx + 3 < n)
    *(int4*)(rs + idx) = r;
  else {
    if (idx < n) rs[idx] = r.x;
    if (idx + 1 < n) rs[idx + 1] = r.y;
    if (idx + 2 < n) rs[idx + 2] = r.z;
    if (idx + 3 < n) rs[idx + 3] = r.w;
  }
  if (blockIdx.x == 0 && t == 0) rs[n] = total;
}

// ---------------- CSR build: fill (consumes cnt as countdown cursor) --------
__global__ __launch_bounds__(256) void k_fill(const int* __restrict__ src,
                                              const int* __restrict__ dst,
                                              const int* __restrict__ rs,
                                              int* __restrict__ cnt,
                                              int* __restrict__ csr, int nE, int soff) {
  int e = blockIdx.x * 256 + threadIdx.x;
  if (e < nE) {
    int d = dst[e];
    int p = atomicSub(&cnt[d], 1);  // old value, 1..deg
    csr[rs[d] + p - 1] = src[e] + soff;
  }
}

// ---------------- mean aggregation: 4 nodes/wave, 16 lanes/node, f16x8 ------
__global__ __launch_bounds__(256) void k_agg3(
    const u16* __restrict__ h_all, const int* __restrict__ csr,
    const int* __restrict__ rs, u16* __restrict__ M_all, int N3) {
  int wave = (blockIdx.x * 256 + threadIdx.x) >> 6;
  int lane = threadIdx.x & 63;
  int l16 = lane & 15;
  int w = wave * 4 + (lane >> 4);
  bool valid = w < N3;
  int wc = valid ? w : 0;
  int e = rs[wc];
  int en = valid ? rs[wc + 1] : 0;
  int deg = en - e;
  f32x2 ac0 = {0.f, 0.f}, ac1 = {0.f, 0.f}, ac2 = {0.f, 0.f}, ac3 = {0.f, 0.f};
  const char* hb = (const char*)h_all;
  unsigned loff = (unsigned)l16 * 16u;

  while (__any(e < en)) {
    bool a0 = e < en, a1 = e + 1 < en;
    int s0 = 0, s1 = 0;
    if (a0) s0 = csr[e];
    if (a1) s1 = csr[e + 1];
    f16x8 v0 = {0, 0, 0, 0, 0, 0, 0, 0}, v1 = {0, 0, 0, 0, 0, 0, 0, 0};
    if (a0) v0 = *(const f16x8*)(hb + ((unsigned)s0 * 256u + loff));
    if (a1) v1 = *(const f16x8*)(hb + ((unsigned)s1 * 256u + loff));
    ac0 += (f32x2){(float)v0[0], (float)v0[1]};
    ac1 += (f32x2){(float)v0[2], (float)v0[3]};
    ac2 += (f32x2){(float)v0[4], (float)v0[5]};
    ac3 += (f32x2){(float)v0[6], (float)v0[7]};
    ac0 += (f32x2){(float)v1[0], (float)v1[1]};
    ac1 += (f32x2){(float)v1[2], (float)v1[3]};
    ac2 += (f32x2){(float)v1[4], (float)v1[5]};
    ac3 += (f32x2){(float)v1[6], (float)v1[7]};
    e += 2;
  }

  if (valid) {
    float inv = deg ? 1.0f / (float)deg : 0.f;
    f16x8 r = {(f16)(ac0[0] * inv), (f16)(ac0[1] * inv),
               (f16)(ac1[0] * inv), (f16)(ac1[1] * inv),
               (f16)(ac2[0] * inv), (f16)(ac2[1] * inv),
               (f16)(ac3[0] * inv), (f16)(ac3[1] * inv)};
    *(f16x8*)((char*)M_all + ((unsigned)wc * 256u + loff)) = r;
  }
}

// ---------------- fused GEMM body ----------------
template <int NE, int OUTF32>
__device__ __forceinline__ void gemm_body(
    f16 (*Wt)[128][136],
    const u16* __restrict__ mA, const u16* __restrict__ mBp,
    const u16* __restrict__ wtA, const u16* __restrict__ wtB,
    const float* __restrict__ bA, const float* __restrict__ bB,
    const int* __restrict__ rsA, const int* __restrict__ rsB,
    u16* __restrict__ o16, float* __restrict__ o32, int M, int blk) {
  int tid = threadIdx.x;
  {
    const f16x8* wa = (const f16x8*)wtA;
    for (int idx = tid; idx < 128 * 16; idx += 256) {
      int n = idx >> 4, c = idx & 15;
      *(f16x8*)&Wt[0][n][c * 8] = wa[idx];
    }
    if (NE == 2) {
      const f16x8* wb = (const f16x8*)wtB;
      for (int idx = tid; idx < 128 * 16; idx += 256) {
        int n = idx >> 4, c = idx & 15;
        *(f16x8*)&Wt[1][n][c * 8] = wb[idx];
      }
    }
  }
  __syncthreads();

  int lane = tid & 63, w = tid >> 6;
  int lr = lane & 15;
  int lk = (lane >> 4) * 8;
  long row0 = (long)blk * 128 + w * 32;

  f32x4 acc[2][8];
#pragma unroll
  for (int rt = 0; rt < 2; rt++)
#pragma unroll
    for (int n = 0; n < 8; n++) acc[rt][n] = (f32x4){0.f, 0.f, 0.f, 0.f};

#pragma unroll
  for (int e = 0; e < NE; ++e) {
    const f16* mm = (const f16*)((e == 0) ? mA : mBp);
#pragma unroll
    for (int ks = 0; ks < 4; ++ks) {
      int k0 = ks * 32 + lk;
      f16x8 bf[8];
#pragma unroll
      for (int n = 0; n < 8; n++) bf[n] = *(const f16x8*)&Wt[e][n * 16 + lr][k0];
#pragma unroll
      for (int rt = 0; rt < 2; rt++) {
        long r = row0 + rt * 16 + lr;
        if (r >= M) r = M - 1;  // clamped load; store guarded
        f16x8 af = *(const f16x8*)(mm + r * D + k0);
#pragma unroll
        for (int n = 0; n < 8; n++)
          acc[rt][n] = __builtin_amdgcn_mfma_f32_16x16x32_f16(af, bf[n], acc[rt][n], 0, 0, 0);
      }
    }
  }

  float bAr[8], bBr[8];
#pragma unroll
  for (int n = 0; n < 8; n++) {
    bAr[n] = bA[n * 16 + lr];
    bBr[n] = (NE == 2) ? bB[n * 16 + lr] : 0.f;
  }

#pragma unroll
  for (int rt = 0; rt < 2; rt++) {
    long rbase = row0 + rt * 16 + (lane >> 4) * 4;
#pragma unroll
    for (int i = 0; i < 4; i++) {
      long r = rbase + i;
      if (r < M) {
        bool mAok = rsA[r + 1] > rsA[r];
        bool mBok = (NE == 2) && (rsB[r + 1] > rsB[r]);
#pragma unroll
        for (int n = 0; n < 8; n++) {
          int col = n * 16 + lr;
          float v = acc[rt][n][i];
          if (mAok) v += bAr[n];
          if (mBok) v += bBr[n];
          v = v > 0.f ? v : 0.01f * v;
          if (OUTF32)
            o32[r * D + col] = v;
          else
            ((f16*)o16)[r * D + col] = (f16)v;
        }
      }
    }
  }
}

// ---------------- fused per-layer GEMM: item blocks + user blocks ----------
template <int OUTF32>
__global__ __launch_bounds__(256) void k_gemm2(
    const u16* __restrict__ M_all, const u16* __restrict__ Wl,
    const float* __restrict__ bl, const int* __restrict__ rs_all,
    u16* __restrict__ h_all, float* __restrict__ out,
    int NU, int NI, int nbI) {
  __shared__ __align__(16) f16 Wt[2][128][136];
  if ((int)blockIdx.x < nbI) {
    // items: hi_next = leaky(Mc @ W1 + mask*b1)
    gemm_body<1, OUTF32>(Wt,
                         M_all + (size_t)NU * D, nullptr,
                         Wl + 16384, nullptr,
                         bl + D, nullptr,
                         rs_all + NU, nullptr,
                         h_all + (size_t)NU * D, out + (size_t)NU * D, NI,
                         blockIdx.x);
  } else {
    // users: hu_next = leaky(Mf @ W0 + Mcb @ W2 + masked biases)
    gemm_body<2, OUTF32>(Wt,
                         M_all, M_all + (size_t)(NU + NI) * D,
                         Wl, Wl + 2 * 16384,
                         bl, bl + 2 * D,
                         rs_all, rs_all + NU + NI,
                         h_all, out, NU, blockIdx.x - nbI);
  }
}

extern "C" void kernel_launch(void* const* d_in, const int* in_sizes, int n_in,
                              void* d_out, int out_size, void* d_ws, size_t ws_size,
                              hipStream_t stream) {
  const float* h_user = (const float*)d_in[0];
  const float* h_item = (const float*)d_in[1];
  const float* W = (const float*)d_in[2];
  const float* bb = (const float*)d_in[3];
  const int* f_src = (const int*)d_in[4];
  const int* f_dst = (const int*)d_in[5];
  const int* c_src = (const int*)d_in[6];
  const int* c_dst = (const int*)d_in[7];
  const int* cb_src = (const int*)d_in[8];
  const int* cb_dst = (const int*)d_in[9];

  const int NU = in_sizes[0] / D;
  const int NI = in_sizes[1] / D;
  const int nEf = in_sizes[4], nEc = in_sizes[6], nEcb = in_sizes[8];
  const int N3 = NU + NI + NU;
  const int nE = nEf + nEc + nEcb;

  char* p = (char*)d_ws;
  auto alloc = [&](size_t bytes) {
    char* r = p;
    p += (bytes + 255) & ~(size_t)255;
    return r;
  };
  int* cnt_all = (int*)alloc((size_t)N3 * 4);
  int* rs_all = (int*)alloc((size_t)(N3 + 1) * 4);
  int* part = (int*)alloc(1024 * 4);
  u16* Wtg = (u16*)alloc((size_t)9 * 16384 * 2);
  int* csr_all = (int*)alloc((size_t)nE * 4);
  u16* h_all = (u16*)alloc((size_t)(NU + NI) * D * 2);  // [hu | hi]
  u16* M_all = (u16*)alloc((size_t)N3 * D * 2);         // [Mf | Mc | Mcb]
  (void)ws_size;

  hipMemsetAsync(cnt_all, 0, (size_t)N3 * 4, stream);

  k_convert<<<(NU * D / 8 + 255) / 256, 256, 0, stream>>>(h_user, h_all, NU * D / 8);
  k_convert<<<(NI * D / 8 + 255) / 256, 256, 0, stream>>>(h_item, h_all + (size_t)NU * D,
                                                          NI * D / 8);
  k_convW<<<(9 * 16384 + 255) / 256, 256, 0, stream>>>(W, Wtg, 9 * 16384);

  k_count<<<(nEf + 255) / 256, 256, 0, stream>>>(f_dst, cnt_all, nEf);
  k_count<<<(nEc + 255) / 256, 256, 0, stream>>>(c_dst, cnt_all + NU, nEc);
  k_count<<<(nEcb + 255) / 256, 256, 0, stream>>>(cb_dst, cnt_all + NU + NI, nEcb);

  int n_part = (N3 + 1023) / 1024;
  k_scanA<<<n_part, 256, 0, stream>>>(cnt_all, part, N3);
  k_scanB<<<1, 1024, 0, stream>>>(part, n_part);
  k_scanC<<<n_part, 256, 0, stream>>>(cnt_all, part, rs_all, N3, nE);

  // fill consumes cnt_all as a countdown cursor; masks later use rs-diffs
  k_fill<<<(nEf + 255) / 256, 256, 0, stream>>>(f_src, f_dst, rs_all, cnt_all,
                                                csr_all, nEf, 0);
  k_fill<<<(nEc + 255) / 256, 256, 0, stream>>>(c_src, c_dst, rs_all + NU, cnt_all + NU,
                                                csr_all, nEc, 0);
  k_fill<<<(nEcb + 255) / 256, 256, 0, stream>>>(cb_src, cb_dst, rs_all + NU + NI,
                                                 cnt_all + NU + NI, csr_all, nEcb, NU);

  int nbI = (NI + 127) / 128;
  int nbU = (NU + 127) / 128;
  int agg_blocks = ((N3 + 3) / 4 + 3) / 4;

  for (int l = 0; l < 3; ++l) {
    const u16* Wl = Wtg + (size_t)l * 3 * 16384;
    const float* bl = bb + (size_t)l * 3 * D;

    k_agg3<<<agg_blocks, 256, 0, stream>>>(h_all, csr_all, rs_all, M_all, N3);

    if (l < 2)
      k_gemm2<0><<<nbI + nbU, 256, 0, stream>>>(M_all, Wl, bl, rs_all, h_all,
                                                (float*)d_out, NU, NI, nbI);
    else
      k_gemm2<1><<<nbI + nbU, 256, 0, stream>>>(M_all, Wl, bl, rs_all, h_all,
                                                (float*)d_out, NU, NI, nbI);
  }
}